// Round 4
// baseline (259.847 us; speedup 1.0000x reference)
//
#include <hip/hip_runtime.h>
#include <hip/hip_bf16.h>

#define SLEN 2048
#define BATCH 2
#define NHQ 16
#define NHKV 8
#define DIM 128

#define VSTRIDE 36   // u32 words per V^T row: 32 key-pairs + pad (16B-aligned)
#define PSTRIDE 72   // bf16 elems per P row: 64 + pad (16B-aligned)

typedef __attribute__((ext_vector_type(8))) short bf16x8;
typedef __attribute__((ext_vector_type(4))) float f32x4;

static __device__ inline short f2bf(float f) {
    __hip_bfloat16 h = __float2bfloat16(f);
    return *reinterpret_cast<short*>(&h);
}
static __device__ inline unsigned pack_bf2(float lo, float hi) {
    unsigned a = (unsigned)(unsigned short)f2bf(lo);
    unsigned b = (unsigned)(unsigned short)f2bf(hi);
    return a | (b << 16);
}

// ---------------------------------------------------------------------------
// Preprocess: run_start / run_end of the contiguous run of 1s containing s.
// rs=-1, re=-2 if mask[s]==0.  bidir-allowed(q,k) <=> rs[q]>=0 && rs[q]==rs[k]
// ---------------------------------------------------------------------------
__global__ void prep_runs(const int* __restrict__ mask,
                          int* __restrict__ rs, int* __restrict__ re) {
    __shared__ int sm[SLEN];
    const int b = blockIdx.x;
    const int* mb = mask + b * SLEN;
    for (int i = threadIdx.x; i < SLEN; i += blockDim.x) sm[i] = mb[i];
    __syncthreads();
    for (int i = threadIdx.x; i < SLEN; i += blockDim.x) {
        int s0 = -1, e0 = -2;
        if (sm[i] == 1) {
            s0 = i; while (s0 > 0 && sm[s0 - 1] == 1) --s0;
            e0 = i; while (e0 < SLEN - 1 && sm[e0 + 1] == 1) ++e0;
        }
        rs[b * SLEN + i] = s0;
        re[b * SLEN + i] = e0;
    }
}

// ---------------------------------------------------------------------------
// MFMA flash attention, pipelined.
// Block = 256 thr = 4 waves per (b, kv-head h, 32-row group):
//   wave w -> head hq = 2h + (w&1), rows r0 = rg*32 + (w>>1)*16.
// Double-buffered V^T tile in LDS, ONE barrier per k-tile; V loads for tile
// i+1 issued right after barrier i; K raw float4s prefetched one c ahead.
// P tile is wave-private bf16 in LDS (no barrier, no cvt on read).
// ---------------------------------------------------------------------------
__global__ __launch_bounds__(256, 2) void attn_fwd(
    const float* __restrict__ Q, const float* __restrict__ K,
    const float* __restrict__ V, const int* __restrict__ rs,
    const int* __restrict__ re, const int* __restrict__ csp,
    float* __restrict__ Out)
{
    const int tid  = threadIdx.x;
    const int wid  = tid >> 6;
    const int lane = tid & 63;
    const int quad = lane >> 4;
    const int n    = lane & 15;

    const int bid   = blockIdx.x;            // 0..1023
    const int rg    = bid & (SLEN / 32 - 1); // 0..63
    const int h     = (bid >> 6) & (NHKV - 1);
    const int b     = bid >> 9;
    const int hq    = 2 * h + (wid & 1);
    const int rbase = rg * 32;
    const int r0    = rbase + (wid >> 1) * 16;

    __shared__ unsigned vt[2][128 * VSTRIDE];  // V^T tiles, bf16-pair packed
    __shared__ short    pls[4][16 * PSTRIDE];  // per-wave P tiles (bf16)

    const float scale = 0.08838834764831845f;  // 1/sqrt(128)
    const int cs      = csp[0];
    const int cstart  = (rbase / cs) * cs;     // same chunk for all 32 rows

    const int* rsb = rs + b * SLEN;
    const int* reb = re + b * SLEN;

    // block k-range: union over the 32 rows (identical in every wave)
    int row_l = rbase + (lane & 31);
    int rsv = rsb[row_l], rev = reb[row_l];
    int lo_r = cstart; if (rsv >= 0 && rsv < lo_r) lo_r = rsv;
    int hi_r = row_l;  if (rev > hi_r) hi_r = rev;
    #pragma unroll
    for (int off = 32; off > 0; off >>= 1) {
        lo_r = min(lo_r, __shfl_xor(lo_r, off, 64));
        hi_r = max(hi_r, __shfl_xor(hi_r, off, 64));
    }
    const int lo_t = lo_r & ~63;
    const int hi_t = hi_r;

    // run ids for the 4 C-layout rows this lane owns (rows r0 + quad*4+g)
    int rsrv[4];
    #pragma unroll
    for (int g = 0; g < 4; ++g) rsrv[g] = rsb[r0 + quad * 4 + g];

    // Q A-frags: A[m=n][k=quad*8+j], 4 k-blocks of 32
    bf16x8 qa[4];
    {
        const float* qp = Q + (((size_t)(b * SLEN + r0 + n) * NHQ + hq) * DIM) + quad * 8;
        #pragma unroll
        for (int kb = 0; kb < 4; ++kb) {
            float4 f0 = *(const float4*)(qp + kb * 32);
            float4 f1 = *(const float4*)(qp + kb * 32 + 4);
            bf16x8 a;
            a[0] = f2bf(f0.x * scale); a[1] = f2bf(f0.y * scale);
            a[2] = f2bf(f0.z * scale); a[3] = f2bf(f0.w * scale);
            a[4] = f2bf(f1.x * scale); a[5] = f2bf(f1.y * scale);
            a[6] = f2bf(f1.z * scale); a[7] = f2bf(f1.w * scale);
            qa[kb] = a;
        }
    }

    float mrow[4], lrow[4];
    f32x4 o[8];
    #pragma unroll
    for (int g = 0; g < 4; ++g) { mrow[g] = -3.0e38f; lrow[g] = 0.0f; }
    #pragma unroll
    for (int nb = 0; nb < 8; ++nb) o[nb] = (f32x4){0.f, 0.f, 0.f, 0.f};

    const float* Kb = K + ((size_t)b * SLEN * NHKV + h) * DIM;
    const float* Vb = V + ((size_t)b * SLEN * NHKV + h) * DIM;
    const size_t kvstride = (size_t)NHKV * DIM;

    const int vc = tid & 127;   // V staging: column (dim)
    const int vk = tid >> 7;    // V staging: pair-phase

    // V prefetch registers (tile in flight)
    float vra[16], vrb[16];
    #pragma unroll
    for (int i = 0; i < 16; ++i) {
        const int j = i * 2 + vk;
        const int r1 = min(lo_t + 2 * j, SLEN - 1);
        const int r2 = min(lo_t + 2 * j + 1, SLEN - 1);
        vra[i] = Vb[(size_t)r1 * kvstride + vc];
        vrb[i] = Vb[(size_t)r2 * kvstride + vc];
    }

    int bufi = 0;
    for (int k0 = lo_t; k0 <= hi_t; k0 += 64, bufi ^= 1) {
        // ---- pack prefetched V -> vt[bufi] ----
        unsigned* vtb = &vt[bufi][0];
        #pragma unroll
        for (int i = 0; i < 16; ++i) {
            const int j = i * 2 + vk;
            vtb[vc * VSTRIDE + j] = pack_bf2(vra[i], vrb[i]);
        }
        __syncthreads();   // vt[bufi] ready; prev buffer's readers all done

        // ---- issue V loads for tile k0+64 (lands during this tile) ----
        {
            const int kn0 = k0 + 64;
            #pragma unroll
            for (int i = 0; i < 16; ++i) {
                const int j = i * 2 + vk;
                const int r1 = min(kn0 + 2 * j, SLEN - 1);
                const int r2 = min(kn0 + 2 * j + 1, SLEN - 1);
                vra[i] = Vb[(size_t)r1 * kvstride + vc];
                vrb[i] = Vb[(size_t)r2 * kvstride + vc];
            }
        }

        // ---- S = Q K^T (16x64), K raw prefetched one c-step ahead ----
        f32x4 sfr[4];
        float4 kf[8];
        {
            const int krow = min(k0 + n, SLEN - 1);
            const float* kp = Kb + (size_t)krow * kvstride + quad * 8;
            #pragma unroll
            for (int u = 0; u < 4; ++u) {
                kf[2 * u]     = *(const float4*)(kp + u * 32);
                kf[2 * u + 1] = *(const float4*)(kp + u * 32 + 4);
            }
        }
        #pragma unroll
        for (int c = 0; c < 4; ++c) {
            float4 kn[8];
            if (c < 3) {
                const int krow = min(k0 + (c + 1) * 16 + n, SLEN - 1);
                const float* kp = Kb + (size_t)krow * kvstride + quad * 8;
                #pragma unroll
                for (int u = 0; u < 4; ++u) {
                    kn[2 * u]     = *(const float4*)(kp + u * 32);
                    kn[2 * u + 1] = *(const float4*)(kp + u * 32 + 4);
                }
            }
            f32x4 acc = (f32x4){0.f, 0.f, 0.f, 0.f};
            #pragma unroll
            for (int kb = 0; kb < 4; ++kb) {
                const float4 f0 = kf[2 * kb];
                const float4 f1 = kf[2 * kb + 1];
                bf16x8 bb;
                bb[0] = f2bf(f0.x); bb[1] = f2bf(f0.y);
                bb[2] = f2bf(f0.z); bb[3] = f2bf(f0.w);
                bb[4] = f2bf(f1.x); bb[5] = f2bf(f1.y);
                bb[6] = f2bf(f1.z); bb[7] = f2bf(f1.w);
                acc = __builtin_amdgcn_mfma_f32_16x16x32_bf16(qa[kb], bb, acc, 0, 0, 0);
            }
            sfr[c] = acc;
            if (c < 3) {
                #pragma unroll
                for (int u = 0; u < 8; ++u) kf[u] = kn[u];
            }
        }

        // ---- mask (skip when tile fully causal-allowed) ----
        const bool fullcausal = (k0 >= cstart) && (k0 + 63 <= r0);
        if (!fullcausal) {
            #pragma unroll
            for (int c = 0; c < 4; ++c) {
                const int kcol = k0 + c * 16 + n;
                const int rsk  = rsb[min(kcol, SLEN - 1)];
                const bool kin = (kcol < SLEN);
                #pragma unroll
                for (int g = 0; g < 4; ++g) {
                    const int r = r0 + quad * 4 + g;
                    const bool ok = kin && (((kcol >= cstart) && (kcol <= r)) ||
                                            (rsrv[g] >= 0 && rsk == rsrv[g]));
                    if (!ok) sfr[c][g] = -3.0e38f;
                }
            }
        }

        // ---- online softmax (rows on 16-lane groups, 4 rows/lane) ----
        float mloc[4] = {-3.0e38f, -3.0e38f, -3.0e38f, -3.0e38f};
        #pragma unroll
        for (int c = 0; c < 4; ++c)
            #pragma unroll
            for (int g = 0; g < 4; ++g) mloc[g] = fmaxf(mloc[g], sfr[c][g]);
        #pragma unroll
        for (int off = 8; off > 0; off >>= 1)
            #pragma unroll
            for (int g = 0; g < 4; ++g)
                mloc[g] = fmaxf(mloc[g], __shfl_xor(mloc[g], off, 64));

        float alpha[4];
        #pragma unroll
        for (int g = 0; g < 4; ++g) {
            const float mnew = fmaxf(mrow[g], mloc[g]);
            alpha[g] = __expf(mrow[g] - mnew);
            mrow[g] = mnew;
        }

        float psum[4] = {0.f, 0.f, 0.f, 0.f};
        #pragma unroll
        for (int c = 0; c < 4; ++c) {
            #pragma unroll
            for (int g = 0; g < 4; ++g) {
                // masked lanes: exp(-3e38 - m) == 0 once m is real; fully-
                // masked-so-far rows carry garbage p==1 that is flushed by
                // alpha==0 when the causal diagonal arrives.
                const float pv = __expf(sfr[c][g] - mrow[g]);
                psum[g] += pv;
                pls[wid][(quad * 4 + g) * PSTRIDE + c * 16 + n] = f2bf(pv);
            }
        }
        #pragma unroll
        for (int off = 8; off > 0; off >>= 1)
            #pragma unroll
            for (int g = 0; g < 4; ++g)
                psum[g] += __shfl_xor(psum[g], off, 64);
        #pragma unroll
        for (int g = 0; g < 4; ++g)
            lrow[g] = lrow[g] * alpha[g] + psum[g];
        #pragma unroll
        for (int nb = 0; nb < 8; ++nb)
            #pragma unroll
            for (int g = 0; g < 4; ++g)
                o[nb][g] *= alpha[g];

        // ---- O += P V : P is wave-private (lgkmcnt only, no barrier) ----
        #pragma unroll
        for (int kb2 = 0; kb2 < 2; ++kb2) {
            bf16x8 pa = *(const bf16x8*)&pls[wid][n * PSTRIDE + kb2 * 32 + quad * 8];
            #pragma unroll
            for (int nb = 0; nb < 8; ++nb) {
                const unsigned* vp = &vtb[(nb * 16 + n) * VSTRIDE + kb2 * 16 + quad * 4];
                bf16x8 vv = *(const bf16x8*)vp;   // 16B aligned
                o[nb] = __builtin_amdgcn_mfma_f32_16x16x32_bf16(pa, vv, o[nb], 0, 0, 0);
            }
        }
    }

    // ---- epilogue ----
    #pragma unroll
    for (int g = 0; g < 4; ++g) {
        const float inv = 1.0f / lrow[g];
        const int r = r0 + quad * 4 + g;
        float* op = Out + ((size_t)(b * SLEN + r) * NHQ + hq) * DIM + n;
        #pragma unroll
        for (int nb = 0; nb < 8; ++nb)
            op[nb * 16] = o[nb][g] * inv;
    }
}

extern "C" void kernel_launch(void* const* d_in, const int* in_sizes, int n_in,
                              void* d_out, int out_size, void* d_ws, size_t ws_size,
                              hipStream_t stream) {
    const float* q  = (const float*)d_in[0];
    const float* k  = (const float*)d_in[1];
    const float* v  = (const float*)d_in[2];
    const int*   bm = (const int*)d_in[3];
    const int*   cs = (const int*)d_in[4];
    float* out = (float*)d_out;

    int* rs = (int*)d_ws;
    int* re = rs + BATCH * SLEN;

    hipLaunchKernelGGL(prep_runs, dim3(BATCH), dim3(256), 0, stream, bm, rs, re);
    hipLaunchKernelGGL(attn_fwd, dim3(BATCH * NHKV * (SLEN / 32)), dim3(256), 0, stream,
                       q, k, v, rs, re, cs, out);
}

// Round 5
// 153.094 us; speedup vs baseline: 1.6973x; 1.6973x over previous
//
#include <hip/hip_runtime.h>
#include <hip/hip_bf16.h>

#define SLEN 2048
#define BATCH 2
#define NHQ 16
#define NHKV 8
#define DIM 128
#define SEG 512              // rows per segment; block = one parity of one segment
#define NSEG (SLEN / SEG)    // 4
#define KVROW (NHKV * DIM)   // 1024 floats

#define KSTR 68              // dwords per K-tile row  (136 bf16 = 128 + 8 pad)
#define VSTR 36              // dwords per V^T row     (72 bf16  = 64 + 8 pad)
#define PSTR 72              // bf16 per P row         (64 + 8 pad)

typedef __attribute__((ext_vector_type(8))) short bf16x8;
typedef __attribute__((ext_vector_type(4))) float f32x4;

static __device__ inline short f2bf(float f) {
    __hip_bfloat16 h = __float2bfloat16(f);
    return *reinterpret_cast<short*>(&h);
}
static __device__ inline unsigned pack_bf2(float lo, float hi) {
    unsigned a = (unsigned)(unsigned short)f2bf(lo);
    unsigned b = (unsigned)(unsigned short)f2bf(hi);
    return a | (b << 16);
}

// ---------------------------------------------------------------------------
// Preprocess: run_start / run_end of the contiguous run of 1s containing s.
// rs=-1, re=-2 if mask[s]==0.  bidir-allowed(q,k) <=> rs[q]>=0 && rs[q]==rs[k]
// ---------------------------------------------------------------------------
__global__ void prep_runs(const int* __restrict__ mask,
                          int* __restrict__ rs, int* __restrict__ re) {
    __shared__ int sm[SLEN];
    const int b = blockIdx.x;
    const int* mb = mask + b * SLEN;
    for (int i = threadIdx.x; i < SLEN; i += blockDim.x) sm[i] = mb[i];
    __syncthreads();
    for (int i = threadIdx.x; i < SLEN; i += blockDim.x) {
        int s0 = -1, e0 = -2;
        if (sm[i] == 1) {
            s0 = i; while (s0 > 0 && sm[s0 - 1] == 1) --s0;
            e0 = i; while (e0 < SLEN - 1 && sm[e0 + 1] == 1) ++e0;
        }
        rs[b * SLEN + i] = s0;
        re[b * SLEN + i] = e0;
    }
}

// ---------------------------------------------------------------------------
// Chunk-resident MFMA flash attention.
// Block = 512 thr = 8 waves = (b, hq, segment, parity). Wave w owns row-tiles
// at rows rbase+(2w+par)*16 and +256. Per 64-key k-tile: K(bf16,[key][d]) and
// V^T(bf16,[d][key]) staged once by the whole block into dbuf LDS (coalesced),
// consumed by all row-tile updates via ds_read_b128. One barrier per tile.
// ---------------------------------------------------------------------------
__global__ __launch_bounds__(512, 2) void attn_fwd(
    const float* __restrict__ Q, const float* __restrict__ K,
    const float* __restrict__ V, const int* __restrict__ rs,
    const int* __restrict__ re, const int* __restrict__ csp,
    float* __restrict__ Out)
{
    const int tid  = threadIdx.x;
    const int wid  = tid >> 6;     // 0..7
    const int lane = tid & 63;
    const int quad = lane >> 4;
    const int n    = lane & 15;

    // XCD-swizzled decode: the 4 blocks sharing (b,h,seg) K/V land on one XCD
    const int bid = blockIdx.x;            // 0..255
    const int xcd = bid & 7;
    const int M   = (bid >> 3) & 3;        // (hq_low, par)
    const int Ghi = bid >> 5;              // 0..7
    const int G   = Ghi * 8 + xcd;         // (b, h, seg) in 0..63
    const int seg = G & 3;
    const int h   = (G >> 2) & 7;
    const int b   = G >> 5;
    const int par = M >> 1;
    const int hq  = h * 2 + (M & 1);

    const int rbase = seg * SEG;
    int r0[2];
    r0[0] = rbase + (2 * wid + par) * 16;
    r0[1] = r0[0] + 256;

    __shared__ unsigned kt[2][64 * KSTR];      // K tiles, bf16 [key][d]
    __shared__ unsigned vt[2][128 * VSTR];     // V^T tiles, bf16 [d][key]
    __shared__ short    pls[8][2][16 * PSTR];  // per-wave P tiles (bf16)
    __shared__ int      smk[2][64];            // per-tile rs[key]
    __shared__ int      wred[16];              // block lo/hi reduce

    const float scale = 0.08838834764831845f;  // 1/sqrt(128)
    const int cs = csp[0];

    const int* rsb = rs + b * SLEN;
    const int* reb = re + b * SLEN;

    // per-row-tile k-range, run ids, chunk starts
    int lo_rt[2], hi_rt[2], rsrv[2][4], csg[2][4], cshi[2];
    #pragma unroll
    for (int u = 0; u < 2; ++u) {
        const int row = r0[u] + n;
        const int rsv = rsb[row];
        const int rev = reb[row];
        const int csr = (row / cs) * cs;
        int lo = csr; if (rsv >= 0 && rsv < lo) lo = rsv;
        int hi = row; if (rev > hi) hi = rev;
        #pragma unroll
        for (int off = 8; off > 0; off >>= 1) {
            lo = min(lo, __shfl_xor(lo, off, 64));
            hi = max(hi, __shfl_xor(hi, off, 64));
        }
        lo_rt[u] = lo; hi_rt[u] = hi;
        #pragma unroll
        for (int g = 0; g < 4; ++g) {
            const int r = r0[u] + quad * 4 + g;
            rsrv[u][g] = rsb[r];
            csg[u][g]  = (r / cs) * cs;
        }
        cshi[u] = ((r0[u] + 15) / cs) * cs;
    }

    // Q A-frags (scaled): qa[u][kb], A[m=n][k=quad*8+j]
    bf16x8 qa[2][4];
    #pragma unroll
    for (int u = 0; u < 2; ++u) {
        const float* qp = Q + (((size_t)(b * SLEN + r0[u] + n) * NHQ + hq) * DIM) + quad * 8;
        #pragma unroll
        for (int kb = 0; kb < 4; ++kb) {
            float4 f0 = *(const float4*)(qp + kb * 32);
            float4 f1 = *(const float4*)(qp + kb * 32 + 4);
            bf16x8 a;
            a[0] = f2bf(f0.x * scale); a[1] = f2bf(f0.y * scale);
            a[2] = f2bf(f0.z * scale); a[3] = f2bf(f0.w * scale);
            a[4] = f2bf(f1.x * scale); a[5] = f2bf(f1.y * scale);
            a[6] = f2bf(f1.z * scale); a[7] = f2bf(f1.w * scale);
            qa[u][kb] = a;
        }
    }

    // block k-range = union over 8 waves
    if (lane == 0) {
        wred[wid * 2]     = min(lo_rt[0], lo_rt[1]);
        wred[wid * 2 + 1] = max(hi_rt[0], hi_rt[1]);
    }
    __syncthreads();
    int lo_blk = 0x7fffffff, hi_blk = 0;
    #pragma unroll
    for (int i = 0; i < 8; ++i) {
        lo_blk = min(lo_blk, wred[2 * i]);
        hi_blk = max(hi_blk, wred[2 * i + 1]);
    }
    lo_blk &= ~63;

    float mrow[2][4], lrow[2][4];
    f32x4 o[2][8];
    #pragma unroll
    for (int u = 0; u < 2; ++u) {
        #pragma unroll
        for (int g = 0; g < 4; ++g) { mrow[u][g] = -3.0e38f; lrow[u][g] = 0.0f; }
        #pragma unroll
        for (int nb = 0; nb < 8; ++nb) o[u][nb] = (f32x4){0.f, 0.f, 0.f, 0.f};
    }

    const float* Kb = K + ((size_t)b * SLEN * NHKV + h) * DIM;
    const float* Vb = V + ((size_t)b * SLEN * NHKV + h) * DIM;

    // staging roles
    const int krow_off = tid >> 3;          // 0..63
    const int kcol     = (tid & 7) * 16;    // 0..112
    const int vd       = tid & 127;         // 0..127
    const int vkey     = (tid >> 7) * 16;   // 0,16,32,48

    float4 kr[4];
    float  vr[16];
    int    rsn = 0;

    // prime prefetch for first tile
    {
        const int krow = min(lo_blk + krow_off, SLEN - 1);
        const float* kp = Kb + (size_t)krow * KVROW + kcol;
        kr[0] = *(const float4*)(kp);
        kr[1] = *(const float4*)(kp + 4);
        kr[2] = *(const float4*)(kp + 8);
        kr[3] = *(const float4*)(kp + 12);
        #pragma unroll
        for (int i = 0; i < 16; ++i)
            vr[i] = Vb[(size_t)min(lo_blk + vkey + i, SLEN - 1) * KVROW + vd];
        if (tid < 64) rsn = rsb[min(lo_blk + tid, SLEN - 1)];
    }

    int bufi = 0;
    for (int k0 = lo_blk; k0 <= hi_blk; k0 += 64, bufi ^= 1) {
        // ---- pack prefetched tile into LDS buf ----
        {
            uint2* kd = (uint2*)&kt[bufi][krow_off * KSTR + (tid & 7) * 8];
            #pragma unroll
            for (int i = 0; i < 4; ++i) {
                uint2 w; w.x = pack_bf2(kr[i].x, kr[i].y); w.y = pack_bf2(kr[i].z, kr[i].w);
                kd[i] = w;
            }
            uint2* vdst = (uint2*)&vt[bufi][vd * VSTR + (tid >> 7) * 8];
            #pragma unroll
            for (int m = 0; m < 4; ++m) {
                uint2 w; w.x = pack_bf2(vr[4 * m], vr[4 * m + 1]);
                w.y = pack_bf2(vr[4 * m + 2], vr[4 * m + 3]);
                vdst[m] = w;
            }
            if (tid < 64) smk[bufi][tid] = rsn;
        }
        __syncthreads();

        // ---- issue prefetch for next tile ----
        if (k0 + 64 <= hi_blk) {
            const int kn0 = k0 + 64;
            const int krow = min(kn0 + krow_off, SLEN - 1);
            const float* kp = Kb + (size_t)krow * KVROW + kcol;
            kr[0] = *(const float4*)(kp);
            kr[1] = *(const float4*)(kp + 4);
            kr[2] = *(const float4*)(kp + 8);
            kr[3] = *(const float4*)(kp + 12);
            #pragma unroll
            for (int i = 0; i < 16; ++i)
                vr[i] = Vb[(size_t)min(kn0 + vkey + i, SLEN - 1) * KVROW + vd];
            if (tid < 64) rsn = rsb[min(kn0 + tid, SLEN - 1)];
        }

        // ---- which of my 2 row-tiles touch this k-tile? (wave-uniform) ----
        bool act[2];
        act[0] = (k0 + 63 >= lo_rt[0]) && (k0 <= hi_rt[0]);
        act[1] = (k0 + 63 >= lo_rt[1]) && (k0 <= hi_rt[1]);
        if (!act[0] && !act[1]) continue;

        const short* ktb = (const short*)&kt[bufi][0];
        const short* vtb = (const short*)&vt[bufi][0];

        // ---- S = Q K^T, K-frag shared across both row-tiles ----
        f32x4 sfr[2][4];
        #pragma unroll
        for (int u = 0; u < 2; ++u)
            #pragma unroll
            for (int c = 0; c < 4; ++c)
                sfr[u][c] = (f32x4){0.f, 0.f, 0.f, 0.f};
        #pragma unroll
        for (int c = 0; c < 4; ++c) {
            #pragma unroll
            for (int kb = 0; kb < 4; ++kb) {
                bf16x8 kf = *(const bf16x8*)(ktb + (c * 16 + n) * 136 + kb * 32 + quad * 8);
                if (act[0]) sfr[0][c] = __builtin_amdgcn_mfma_f32_16x16x32_bf16(qa[0][kb], kf, sfr[0][c], 0, 0, 0);
                if (act[1]) sfr[1][c] = __builtin_amdgcn_mfma_f32_16x16x32_bf16(qa[1][kb], kf, sfr[1][c], 0, 0, 0);
            }
        }

        // ---- mask ----
        int rskv[4];
        #pragma unroll
        for (int c = 0; c < 4; ++c) rskv[c] = smk[bufi][c * 16 + n];
        #pragma unroll
        for (int u = 0; u < 2; ++u) {
            if (!act[u]) continue;
            const bool fullc = (k0 >= cshi[u]) && (k0 + 63 <= r0[u]);
            if (!fullc) {
                #pragma unroll
                for (int c = 0; c < 4; ++c) {
                    const int kcl = k0 + c * 16 + n;
                    const bool kin = (kcl < SLEN);
                    #pragma unroll
                    for (int g = 0; g < 4; ++g) {
                        const int r = r0[u] + quad * 4 + g;
                        const bool ok = kin && (((kcl >= csg[u][g]) && (kcl <= r)) ||
                                                (rsrv[u][g] >= 0 && rskv[c] == rsrv[u][g]));
                        if (!ok) sfr[u][c][g] = -3.0e38f;
                    }
                }
            }
        }

        // ---- online softmax + P store (per active row-tile) ----
        #pragma unroll
        for (int u = 0; u < 2; ++u) {
            if (!act[u]) continue;
            float mloc[4] = {-3.0e38f, -3.0e38f, -3.0e38f, -3.0e38f};
            #pragma unroll
            for (int c = 0; c < 4; ++c)
                #pragma unroll
                for (int g = 0; g < 4; ++g) mloc[g] = fmaxf(mloc[g], sfr[u][c][g]);
            #pragma unroll
            for (int off = 8; off > 0; off >>= 1)
                #pragma unroll
                for (int g = 0; g < 4; ++g)
                    mloc[g] = fmaxf(mloc[g], __shfl_xor(mloc[g], off, 64));

            float alpha[4];
            #pragma unroll
            for (int g = 0; g < 4; ++g) {
                const float mnew = fmaxf(mrow[u][g], mloc[g]);
                alpha[g] = __expf(mrow[u][g] - mnew);
                mrow[u][g] = mnew;
            }

            float psum[4] = {0.f, 0.f, 0.f, 0.f};
            #pragma unroll
            for (int c = 0; c < 4; ++c) {
                #pragma unroll
                for (int g = 0; g < 4; ++g) {
                    // masked: exp(-3e38-m)=0 once m real; fully-masked-so-far
                    // rows carry p==1 garbage flushed by alpha==0 at diagonal.
                    const float pv = __expf(sfr[u][c][g] - mrow[u][g]);
                    psum[g] += pv;
                    pls[wid][u][(quad * 4 + g) * PSTR + c * 16 + n] = f2bf(pv);
                }
            }
            #pragma unroll
            for (int off = 8; off > 0; off >>= 1)
                #pragma unroll
                for (int g = 0; g < 4; ++g)
                    psum[g] += __shfl_xor(psum[g], off, 64);
            #pragma unroll
            for (int g = 0; g < 4; ++g)
                lrow[u][g] = lrow[u][g] * alpha[g] + psum[g];
            #pragma unroll
            for (int nb = 0; nb < 8; ++nb)
                #pragma unroll
                for (int g = 0; g < 4; ++g)
                    o[u][nb][g] *= alpha[g];
        }

        // ---- O += P V, V-frag shared across both row-tiles ----
        #pragma unroll
        for (int kb2 = 0; kb2 < 2; ++kb2) {
            bf16x8 pa0, pa1;
            if (act[0]) pa0 = *(const bf16x8*)&pls[wid][0][n * PSTR + kb2 * 32 + quad * 8];
            if (act[1]) pa1 = *(const bf16x8*)&pls[wid][1][n * PSTR + kb2 * 32 + quad * 8];
            #pragma unroll
            for (int nb = 0; nb < 8; ++nb) {
                bf16x8 vf = *(const bf16x8*)(vtb + (nb * 16 + n) * 72 + kb2 * 32 + quad * 8);
                if (act[0]) o[0][nb] = __builtin_amdgcn_mfma_f32_16x16x32_bf16(pa0, vf, o[0][nb], 0, 0, 0);
                if (act[1]) o[1][nb] = __builtin_amdgcn_mfma_f32_16x16x32_bf16(pa1, vf, o[1][nb], 0, 0, 0);
            }
        }
    }

    // ---- epilogue ----
    #pragma unroll
    for (int u = 0; u < 2; ++u) {
        #pragma unroll
        for (int g = 0; g < 4; ++g) {
            const float inv = 1.0f / lrow[u][g];
            const int r = r0[u] + quad * 4 + g;
            float* op = Out + ((size_t)(b * SLEN + r) * NHQ + hq) * DIM + n;
            #pragma unroll
            for (int nb = 0; nb < 8; ++nb)
                op[nb * 16] = o[u][nb][g] * inv;
        }
    }
}

extern "C" void kernel_launch(void* const* d_in, const int* in_sizes, int n_in,
                              void* d_out, int out_size, void* d_ws, size_t ws_size,
                              hipStream_t stream) {
    const float* q  = (const float*)d_in[0];
    const float* k  = (const float*)d_in[1];
    const float* v  = (const float*)d_in[2];
    const int*   bm = (const int*)d_in[3];
    const int*   cs = (const int*)d_in[4];
    float* out = (float*)d_out;

    int* rs = (int*)d_ws;
    int* re = rs + BATCH * SLEN;

    hipLaunchKernelGGL(prep_runs, dim3(BATCH), dim3(256), 0, stream, bm, rs, re);
    hipLaunchKernelGGL(attn_fwd, dim3(BATCH * NHQ * NSEG * 2), dim3(512), 0, stream,
                       q, k, v, rs, re, cs, out);
}